// Round 7
// baseline (427.222 us; speedup 1.0000x reference)
//
#include <hip/hip_runtime.h>
#include <math.h>

#define HDIM 256

typedef float floatx4 __attribute__((ext_vector_type(4)));
typedef __bf16 bf16x8 __attribute__((ext_vector_type(8)));
typedef unsigned short ushortx4 __attribute__((ext_vector_type(4)));

#define AS1C(p) ((const __attribute__((address_space(1))) void*)(p))
#define AS3(p)  ((__attribute__((address_space(3))) void*)(p))

__device__ inline unsigned short bf16_rn(float f) {
  unsigned u = __float_as_uint(f);
  return (unsigned short)((u + 0x7FFFu + ((u >> 16) & 1u)) >> 16);
}

__device__ inline void split_f32(float f, unsigned short& h, unsigned short& l) {
  unsigned short hb = bf16_rn(f);
  float hf = __uint_as_float(((unsigned)hb) << 16);
  h = hb;
  l = bf16_rn(f - hf);
}

// ---------------- weight prep: W[K][256] fp32 -> staged hi/lo bf16 in tile order ----------------
// idx = ((cb*(K/32) + kt)*512 + kc*128 + col); chunk = W[kt*32+kc*8 + e][cb*128+col], e=0..7.

__global__ __launch_bounds__(256)
void prep_w_staged(const float* __restrict__ W, unsigned short* __restrict__ SH,
                   unsigned short* __restrict__ SL, int K) {
  int idx = blockIdx.x * 256 + threadIdx.x;
  int total = K * 32;
  if (idx >= total) return;
  int chunksPerCb = total >> 1;
  int cb = (idx >= chunksPerCb) ? 1 : 0;
  int rem = idx - cb * chunksPerCb;
  int kt = rem >> 9;
  int chunk = rem & 511;
  int kc = chunk >> 7;
  int col = chunk & 127;
  const float* src = W + (size_t)(kt * 32 + kc * 8) * HDIM + cb * 128 + col;
#pragma unroll
  for (int e = 0; e < 8; ++e) {
    unsigned short h, l;
    split_f32(src[(size_t)e * HDIM], h, l);
    SH[(size_t)idx * 8 + e] = h;
    SL[(size_t)idx * 8 + e] = l;
  }
}

// ---------------- CSR build ----------------

__global__ __launch_bounds__(256)
void deg_count_kernel(const int* __restrict__ ei, int* __restrict__ deg, int E) {
  int e = blockIdx.x * 256 + threadIdx.x;
  if (e < E) atomicAdd(&deg[ei[E + e]], 1);
}

__global__ __launch_bounds__(256)
void dinv_kernel(const int* __restrict__ deg, float* __restrict__ dinv, int n) {
  int i = blockIdx.x * 256 + threadIdx.x;
  if (i < n) dinv[i] = 1.0f / sqrtf((float)deg[i] + 1.0f);
}

__global__ __launch_bounds__(256)
void block_sum_kernel(const int* __restrict__ deg, int* __restrict__ bsum, int n) {
  __shared__ int sm[256];
  int t = threadIdx.x;
  int idx = blockIdx.x * 256 + t;
  sm[t] = (idx < n) ? deg[idx] : 0;
  __syncthreads();
  for (int off = 128; off > 0; off >>= 1) {
    if (t < off) sm[t] += sm[t + off];
    __syncthreads();
  }
  if (t == 0) bsum[blockIdx.x] = sm[0];
}

__global__ __launch_bounds__(256)
void scan_bsums_kernel(const int* __restrict__ bsum, int* __restrict__ boff,
                       int* __restrict__ rowptr, int nb, int n) {
  __shared__ int sm[256];
  int t = threadIdx.x;
  int v = (t < nb) ? bsum[t] : 0;
  sm[t] = v;
  __syncthreads();
  for (int off = 1; off < 256; off <<= 1) {
    int a = (t >= off) ? sm[t - off] : 0;
    __syncthreads();
    sm[t] += a;
    __syncthreads();
  }
  if (t < nb) boff[t] = sm[t] - v;
  if (t == 255) rowptr[n] = sm[255];
}

__global__ __launch_bounds__(256)
void scan_final_kernel(const int* __restrict__ deg, const int* __restrict__ boff,
                       int* __restrict__ rowptr, int* __restrict__ cursor, int n) {
  __shared__ int sm[256];
  int t = threadIdx.x;
  int idx = blockIdx.x * 256 + t;
  int v = (idx < n) ? deg[idx] : 0;
  sm[t] = v;
  __syncthreads();
  for (int off = 1; off < 256; off <<= 1) {
    int a = (t >= off) ? sm[t - off] : 0;
    __syncthreads();
    sm[t] += a;
    __syncthreads();
  }
  int excl = sm[t] - v + boff[blockIdx.x];
  if (idx < n) { rowptr[idx] = excl; cursor[idx] = excl; }
}

__global__ __launch_bounds__(256)
void fill_csr_kernel(const int* __restrict__ ei, int* __restrict__ cursor,
                     int* __restrict__ col, int E) {
  int e = blockIdx.x * 256 + threadIdx.x;
  if (e < E) {
    int s = ei[e];
    int d = ei[E + e];
    int p = atomicAdd(&cursor[d], 1);
    col[p] = s;
  }
}

// ---------------- GEMM 1: A fp32 (split in-kernel), tile 128x128, staged B, writes planes ----------------

template<bool BIAS, bool RELU>
__global__ __launch_bounds__(256, 3)
void mfma_gemm_splitA(const float* __restrict__ A,
                      const unsigned short* __restrict__ SWH,
                      const unsigned short* __restrict__ SWL,
                      const float* __restrict__ bias,
                      unsigned short* __restrict__ CH, unsigned short* __restrict__ CL,
                      int M, int K) {
  __shared__ __align__(16) unsigned short AsH[128 * 40];
  __shared__ __align__(16) unsigned short AsL[128 * 40];
  __shared__ __align__(16) unsigned short BsH[4096];
  __shared__ __align__(16) unsigned short BsL[4096];

  const int tid = threadIdx.x;
  const int w = tid >> 6;
  const int l = tid & 63;
  const int l15 = l & 15;
  const int quad = l >> 4;
  const int wm = w & 1;
  const int wn = w >> 1;
  const int bm = blockIdx.y * 128;
  const int bn = blockIdx.x * 128;
  const int ktc = K >> 5;

  floatx4 acc[4][4];
#pragma unroll
  for (int i = 0; i < 4; ++i)
#pragma unroll
    for (int j = 0; j < 4; ++j) acc[i][j] = (floatx4){0.f, 0.f, 0.f, 0.f};

  for (int kt = 0; kt < ktc; ++kt) {
    int k0 = kt * 32;
    float4 av[4];
#pragma unroll
    for (int i = 0; i < 4; ++i) {
      int chunk = i * 256 + tid;
      int row = chunk >> 3;
      int kc4 = chunk & 7;
      int grow = bm + row;
      if (grow > M - 1) grow = M - 1;
      av[i] = *(const float4*)(A + (size_t)grow * K + k0 + kc4 * 4);
    }

    __syncthreads();

    size_t wb = ((size_t)(blockIdx.x * ktc + kt)) * 4096;
#pragma unroll
    for (int j = 0; j < 2; ++j) {
      int c = j * 256 + tid;
      __builtin_amdgcn_global_load_lds(AS1C(SWH + wb + (size_t)c * 8),
                                       AS3(&BsH[(j * 256 + w * 64) * 8]), 16, 0, 0);
      __builtin_amdgcn_global_load_lds(AS1C(SWL + wb + (size_t)c * 8),
                                       AS3(&BsL[(j * 256 + w * 64) * 8]), 16, 0, 0);
    }

#pragma unroll
    for (int i = 0; i < 4; ++i) {
      int chunk = i * 256 + tid;
      int row = chunk >> 3;
      int kc4 = chunk & 7;
      unsigned short h0, h1, h2, h3, l0, l1, l2, l3;
      split_f32(av[i].x, h0, l0);
      split_f32(av[i].y, h1, l1);
      split_f32(av[i].z, h2, l2);
      split_f32(av[i].w, h3, l3);
      *(ushortx4*)&AsH[row * 40 + kc4 * 4] = (ushortx4){h0, h1, h2, h3};
      *(ushortx4*)&AsL[row * 40 + kc4 * 4] = (ushortx4){l0, l1, l2, l3};
    }

    __syncthreads();

    bf16x8 aH[4], aL[4];
#pragma unroll
    for (int fi = 0; fi < 4; ++fi) {
      int row = wm * 64 + fi * 16 + l15;
      aH[fi] = *(const bf16x8*)&AsH[row * 40 + quad * 8];
      aL[fi] = *(const bf16x8*)&AsL[row * 40 + quad * 8];
    }
#pragma unroll
    for (int fj = 0; fj < 4; ++fj) {
      int colL = wn * 64 + fj * 16 + l15;
      int cidx = quad * 128 + colL;
      bf16x8 bh = *(const bf16x8*)&BsH[cidx * 8];
      bf16x8 bl = *(const bf16x8*)&BsL[cidx * 8];
#pragma unroll
      for (int fi = 0; fi < 4; ++fi) {
        floatx4 t = acc[fi][fj];
        t = __builtin_amdgcn_mfma_f32_16x16x32_bf16(aH[fi], bl, t, 0, 0, 0);
        t = __builtin_amdgcn_mfma_f32_16x16x32_bf16(aL[fi], bh, t, 0, 0, 0);
        t = __builtin_amdgcn_mfma_f32_16x16x32_bf16(aH[fi], bh, t, 0, 0, 0);
        acc[fi][fj] = t;
      }
    }
  }

  float bcol[4];
#pragma unroll
  for (int fj = 0; fj < 4; ++fj)
    bcol[fj] = BIAS ? bias[bn + wn * 64 + fj * 16 + l15] : 0.f;

#pragma unroll
  for (int fi = 0; fi < 4; ++fi) {
    int rb = bm + wm * 64 + fi * 16 + quad * 4;
#pragma unroll
    for (int r = 0; r < 4; ++r) {
      int row = rb + r;
      if (row < M) {
        size_t base = (size_t)row * HDIM + bn + wn * 64 + l15;
#pragma unroll
        for (int fj = 0; fj < 4; ++fj) {
          float v = acc[fi][fj][r] + bcol[fj];
          if (RELU) v = fmaxf(v, 0.f);
          unsigned short h, lo;
          split_f32(v, h, lo);
          CH[base + fj * 16] = h;
          CL[base + fj * 16] = lo;
        }
      }
    }
  }
}

// ---------------- pipelined plane GEMM: dbuf LDS + raw barriers + fine vmcnt ----------------
// Tile 128x128, K=256 (8 k-tiles, fully unrolled). Per iter: issue 8 prefetch
// global_load_lds into nxt buffer; s_waitcnt vmcnt(8) (cur's 8 done, prefetch in
// flight); s_barrier; compute. Never drains vmcnt to 0 mid-loop (AITER pattern).

template<bool BIAS, bool RELU, bool SPLIT_OUT>
__global__ __launch_bounds__(256, 2)
void mfma_gemm_pp(const unsigned short* __restrict__ AH, const unsigned short* __restrict__ AL,
                  const unsigned short* __restrict__ SWH, const unsigned short* __restrict__ SWL,
                  const float* __restrict__ bias,
                  float* __restrict__ C, unsigned short* __restrict__ CH,
                  unsigned short* __restrict__ CL, int M) {
  // double-buffered: 4 arrays x 2 x 4096 ushorts = 64 KB
  __shared__ __align__(16) unsigned short AsH[2][4096];
  __shared__ __align__(16) unsigned short AsL[2][4096];
  __shared__ __align__(16) unsigned short BsH[2][4096];
  __shared__ __align__(16) unsigned short BsL[2][4096];

  const int tid = threadIdx.x;
  const int w = tid >> 6;
  const int l = tid & 63;
  const int l15 = l & 15;
  const int quad = l >> 4;
  const int wm = w & 1;
  const int wn = w >> 1;
  const int bm = blockIdx.y * 128;

  // --- precompute per-lane global bases (kt=0) and wave-uniform LDS chunk offsets ---
  const unsigned short* gA_H[2];
  const unsigned short* gA_L[2];
  int ldsA[2];
#pragma unroll
  for (int i = 0; i < 2; ++i) {
    int L = i * 256 + tid;
    int row = L >> 2;
    int p = L & 3;
    int kc = p ^ (row & 3) ^ ((row >> 2) & 3);
    int grow = bm + row;
    if (grow > M - 1) grow = M - 1;
    gA_H[i] = AH + (size_t)grow * HDIM + kc * 8;
    gA_L[i] = AL + (size_t)grow * HDIM + kc * 8;
    ldsA[i] = (i * 256 + w * 64) * 8;   // wave-uniform base; lane lands at +l*8
  }
  const unsigned short* gB_H[2];
  const unsigned short* gB_L[2];
  int ldsB[2];
  {
    size_t wb = (size_t)blockIdx.x * 8 * 4096;
#pragma unroll
    for (int j = 0; j < 2; ++j) {
      int c = j * 256 + tid;
      gB_H[j] = SWH + wb + (size_t)c * 8;
      gB_L[j] = SWL + wb + (size_t)c * 8;
      ldsB[j] = (j * 256 + w * 64) * 8;
    }
  }

  floatx4 acc[4][4];
#pragma unroll
  for (int i = 0; i < 4; ++i)
#pragma unroll
    for (int j = 0; j < 4; ++j) acc[i][j] = (floatx4){0.f, 0.f, 0.f, 0.f};

  // a-frag read positions (swizzle matches staging kc permutation)
  int aOff[4];
#pragma unroll
  for (int fi = 0; fi < 4; ++fi) {
    int r = wm * 64 + fi * 16 + l15;
    int sw = quad ^ (r & 3) ^ ((r >> 2) & 3);
    aOff[fi] = (r * 4 + sw) * 8;
  }

  auto issue = [&](int kt, int b) {
#pragma unroll
    for (int i = 0; i < 2; ++i) {
      __builtin_amdgcn_global_load_lds(AS1C(gA_H[i] + kt * 32), AS3(&AsH[b][ldsA[i]]), 16, 0, 0);
      __builtin_amdgcn_global_load_lds(AS1C(gA_L[i] + kt * 32), AS3(&AsL[b][ldsA[i]]), 16, 0, 0);
    }
#pragma unroll
    for (int j = 0; j < 2; ++j) {
      __builtin_amdgcn_global_load_lds(AS1C(gB_H[j] + (size_t)kt * 4096), AS3(&BsH[b][ldsB[j]]), 16, 0, 0);
      __builtin_amdgcn_global_load_lds(AS1C(gB_L[j] + (size_t)kt * 4096), AS3(&BsL[b][ldsB[j]]), 16, 0, 0);
    }
  };

  issue(0, 0);

#pragma unroll
  for (int kt = 0; kt < 8; ++kt) {
    const int cur = kt & 1;
    // all waves done computing the buffer we are about to overwrite
    __builtin_amdgcn_s_barrier();
    if (kt < 7) {
      issue(kt + 1, cur ^ 1);
      __builtin_amdgcn_s_waitcnt(0xF78);   // vmcnt(8): own cur loads done, prefetch in flight
    } else {
      __builtin_amdgcn_s_waitcnt(0xF70);   // vmcnt(0): last tile
    }
    __builtin_amdgcn_s_barrier();          // everyone's cur tile resident in LDS

    bf16x8 aH[4], aL[4];
#pragma unroll
    for (int fi = 0; fi < 4; ++fi) {
      aH[fi] = *(const bf16x8*)&AsH[cur][aOff[fi]];
      aL[fi] = *(const bf16x8*)&AsL[cur][aOff[fi]];
    }
#pragma unroll
    for (int fj = 0; fj < 4; ++fj) {
      int colL = wn * 64 + fj * 16 + l15;
      int cidx = quad * 128 + colL;
      bf16x8 bh = *(const bf16x8*)&BsH[cur][cidx * 8];
      bf16x8 bl = *(const bf16x8*)&BsL[cur][cidx * 8];
#pragma unroll
      for (int fi = 0; fi < 4; ++fi) {
        floatx4 t = acc[fi][fj];
        t = __builtin_amdgcn_mfma_f32_16x16x32_bf16(aH[fi], bl, t, 0, 0, 0);
        t = __builtin_amdgcn_mfma_f32_16x16x32_bf16(aL[fi], bh, t, 0, 0, 0);
        t = __builtin_amdgcn_mfma_f32_16x16x32_bf16(aH[fi], bh, t, 0, 0, 0);
        acc[fi][fj] = t;
      }
    }
  }

  const int bn = blockIdx.x * 128;
  float bcol[4];
#pragma unroll
  for (int fj = 0; fj < 4; ++fj)
    bcol[fj] = BIAS ? bias[bn + wn * 64 + fj * 16 + l15] : 0.f;

#pragma unroll
  for (int fi = 0; fi < 4; ++fi) {
    int rb = bm + wm * 64 + fi * 16 + quad * 4;
#pragma unroll
    for (int r = 0; r < 4; ++r) {
      int row = rb + r;
      if (row < M) {
        size_t base = (size_t)row * HDIM + bn + wn * 64 + l15;
        if (SPLIT_OUT) {
#pragma unroll
          for (int fj = 0; fj < 4; ++fj) {
            float v = acc[fi][fj][r] + bcol[fj];
            if (RELU) v = fmaxf(v, 0.f);
            unsigned short h, lo;
            split_f32(v, h, lo);
            CH[base + fj * 16] = h;
            CL[base + fj * 16] = lo;
          }
        } else {
#pragma unroll
          for (int fj = 0; fj < 4; ++fj) {
            float v = acc[fi][fj][r] + bcol[fj];
            if (RELU) v = fmaxf(v, 0.f);
            C[base + fj * 16] = v;
          }
        }
      }
    }
  }
}

// ---------------- fused GEMM + softmax: tile 128x256, 512 threads, in-place safe ----------------

__global__ __launch_bounds__(512, 4)
void mfma_gemm_softmax(const unsigned short* __restrict__ AH, const unsigned short* __restrict__ AL,
                       const unsigned short* __restrict__ SWH, const unsigned short* __restrict__ SWL,
                       const float* __restrict__ bias, float* __restrict__ out, int M, int K) {
  __shared__ __align__(16) unsigned short AsH[4096];
  __shared__ __align__(16) unsigned short AsL[4096];
  __shared__ __align__(16) unsigned short BsH[8192];
  __shared__ __align__(16) unsigned short BsL[8192];
  __shared__ float smax[128 * 4];
  __shared__ float ssum[128 * 4];

  const int tid = threadIdx.x;
  const int w = tid >> 6;
  const int l = tid & 63;
  const int l15 = l & 15;
  const int quad = l >> 4;
  const int wm = w & 1;
  const int wn = w >> 1;
  const int bm = blockIdx.x * 128;
  const int ktc = K >> 5;
  const int chunksPerCb = ktc * 512;

  floatx4 acc[4][4];
#pragma unroll
  for (int i = 0; i < 4; ++i)
#pragma unroll
    for (int j = 0; j < 4; ++j) acc[i][j] = (floatx4){0.f, 0.f, 0.f, 0.f};

  for (int kt = 0; kt < ktc; ++kt) {
    __syncthreads();

    {
      int L = tid;
      int row = L >> 2;
      int p = L & 3;
      int kc = p ^ (row & 3) ^ ((row >> 2) & 3);
      int grow = bm + row;
      if (grow > M - 1) grow = M - 1;
      const unsigned short* gH = AH + (size_t)grow * K + kt * 32 + kc * 8;
      const unsigned short* gL = AL + (size_t)grow * K + kt * 32 + kc * 8;
      __builtin_amdgcn_global_load_lds(AS1C(gH), AS3(&AsH[(w * 64) * 8]), 16, 0, 0);
      __builtin_amdgcn_global_load_lds(AS1C(gL), AS3(&AsL[(w * 64) * 8]), 16, 0, 0);
    }
#pragma unroll
    for (int j = 0; j < 2; ++j) {
      int pos = j * 512 + w * 64 + l;
      int kc = pos >> 8;
      int within = pos & 255;
      int cb = within >> 7;
      int colL = within & 127;
      size_t gi = (size_t)cb * chunksPerCb + (size_t)kt * 512 + kc * 128 + colL;
      __builtin_amdgcn_global_load_lds(AS1C(SWH + gi * 8),
                                       AS3(&BsH[(j * 512 + w * 64) * 8]), 16, 0, 0);
      __builtin_amdgcn_global_load_lds(AS1C(SWL + gi * 8),
                                       AS3(&BsL[(j * 512 + w * 64) * 8]), 16, 0, 0);
    }

    __syncthreads();

    bf16x8 aH[4], aL[4];
#pragma unroll
    for (int fi = 0; fi < 4; ++fi) {
      int r = wm * 64 + fi * 16 + l15;
      int sw = quad ^ (r & 3) ^ ((r >> 2) & 3);
      aH[fi] = *(const bf16x8*)&AsH[(r * 4 + sw) * 8];
      aL[fi] = *(const bf16x8*)&AsL[(r * 4 + sw) * 8];
    }
#pragma unroll
    for (int fj = 0; fj < 4; ++fj) {
      int colG = wn * 64 + fj * 16 + l15;
      int cidx = quad * 256 + colG;
      bf16x8 bh = *(const bf16x8*)&BsH[cidx * 8];
      bf16x8 bl = *(const bf16x8*)&BsL[cidx * 8];
#pragma unroll
      for (int fi = 0; fi < 4; ++fi) {
        floatx4 t = acc[fi][fj];
        t = __builtin_amdgcn_mfma_f32_16x16x32_bf16(aH[fi], bl, t, 0, 0, 0);
        t = __builtin_amdgcn_mfma_f32_16x16x32_bf16(aL[fi], bh, t, 0, 0, 0);
        t = __builtin_amdgcn_mfma_f32_16x16x32_bf16(aH[fi], bh, t, 0, 0, 0);
        acc[fi][fj] = t;
      }
    }
  }

  float bcol[4];
#pragma unroll
  for (int fj = 0; fj < 4; ++fj)
    bcol[fj] = bias[wn * 64 + fj * 16 + l15];

#pragma unroll
  for (int fi = 0; fi < 4; ++fi) {
#pragma unroll
    for (int r = 0; r < 4; ++r) {
      float mv = -3.4e38f;
#pragma unroll
      for (int fj = 0; fj < 4; ++fj) mv = fmaxf(mv, acc[fi][fj][r] + bcol[fj]);
#pragma unroll
      for (int off = 1; off < 16; off <<= 1) mv = fmaxf(mv, __shfl_xor(mv, off));
      int row = wm * 64 + fi * 16 + quad * 4 + r;
      if (l15 == 0) smax[row * 4 + wn] = mv;
    }
  }
  __syncthreads();

#pragma unroll
  for (int fi = 0; fi < 4; ++fi) {
#pragma unroll
    for (int r = 0; r < 4; ++r) {
      int row = wm * 64 + fi * 16 + quad * 4 + r;
      float gm = fmaxf(fmaxf(smax[row * 4 + 0], smax[row * 4 + 1]),
                       fmaxf(smax[row * 4 + 2], smax[row * 4 + 3]));
      float s = 0.f;
#pragma unroll
      for (int fj = 0; fj < 4; ++fj) {
        float p = expf(acc[fi][fj][r] + bcol[fj] - gm);
        acc[fi][fj][r] = p;
        s += p;
      }
#pragma unroll
      for (int off = 1; off < 16; off <<= 1) s += __shfl_xor(s, off);
      if (l15 == 0) ssum[row * 4 + wn] = s;
    }
  }
  __syncthreads();

#pragma unroll
  for (int fi = 0; fi < 4; ++fi) {
#pragma unroll
    for (int r = 0; r < 4; ++r) {
      int row = wm * 64 + fi * 16 + quad * 4 + r;
      int grow = bm + row;
      if (grow < M) {
        float inv = 1.0f / (ssum[row * 4 + 0] + ssum[row * 4 + 1] +
                            ssum[row * 4 + 2] + ssum[row * 4 + 3]);
        float* Cp = out + (size_t)grow * HDIM + wn * 64 + l15;
#pragma unroll
        for (int fj = 0; fj < 4; ++fj) Cp[fj * 16] = acc[fi][fj][r] * inv;
      }
    }
  }
}

// ---------------- GCN aggregation: two-phase batched gather (MLP~8), plane output ----------------

__global__ __launch_bounds__(256)
void aggregate_b(const float* __restrict__ t, const float* __restrict__ dinv,
                 const int* __restrict__ rowptr, const int* __restrict__ col,
                 const float* __restrict__ bias,
                 unsigned short* __restrict__ OH, unsigned short* __restrict__ OL, int n) {
  int gw = (int)((blockIdx.x * 256 + threadIdx.x) >> 6);
  int lane = threadIdx.x & 63;
  if (gw >= n) return;
  float di = dinv[gw];
  float4 v = ((const float4*)(t + (size_t)gw * HDIM))[lane];
  float ss = di * di;
  float a0 = v.x * ss, a1 = v.y * ss, a2 = v.z * ss, a3 = v.w * ss;
  int e0 = rowptr[gw], e1 = rowptr[gw + 1];

  for (int base = e0; base < e1; base += 8) {
    int cs[8];
#pragma unroll
    for (int i = 0; i < 8; ++i) {
      int e = base + i;
      if (e > e1 - 1) e = e1 - 1;
      cs[i] = col[e];
    }
    float wg[8];
#pragma unroll
    for (int i = 0; i < 8; ++i)
      wg[i] = (base + i < e1) ? dinv[cs[i]] * di : 0.f;
    float4 rw[8];
#pragma unroll
    for (int i = 0; i < 8; ++i)
      rw[i] = ((const float4*)(t + (size_t)cs[i] * HDIM))[lane];
#pragma unroll
    for (int i = 0; i < 8; ++i) {
      a0 = fmaf(rw[i].x, wg[i], a0);
      a1 = fmaf(rw[i].y, wg[i], a1);
      a2 = fmaf(rw[i].z, wg[i], a2);
      a3 = fmaf(rw[i].w, wg[i], a3);
    }
  }

  float4 bb = ((const float4*)bias)[lane];
  float r0 = fmaxf(a0 + bb.x, 0.f);
  float r1 = fmaxf(a1 + bb.y, 0.f);
  float r2 = fmaxf(a2 + bb.z, 0.f);
  float r3 = fmaxf(a3 + bb.w, 0.f);
  unsigned short h0, h1, h2, h3, l0, l1, l2, l3;
  split_f32(r0, h0, l0);
  split_f32(r1, h1, l1);
  split_f32(r2, h2, l2);
  split_f32(r3, h3, l3);
  ((ushortx4*)(OH + (size_t)gw * HDIM))[lane] = (ushortx4){h0, h1, h2, h3};
  ((ushortx4*)(OL + (size_t)gw * HDIM))[lane] = (ushortx4){l0, l1, l2, l3};
}

// ---------------- launch ----------------

extern "C" void kernel_launch(void* const* d_in, const int* in_sizes, int n_in,
                              void* d_out, int out_size, void* d_ws, size_t ws_size,
                              hipStream_t stream) {
  const float* x   = (const float*)d_in[0];
  const int*   ei  = (const int*)d_in[1];
  const float* W1  = (const float*)d_in[2];
  const float* b1  = (const float*)d_in[3];
  const float* Wg1 = (const float*)d_in[4];
  const float* bg1 = (const float*)d_in[5];
  const float* Wg2 = (const float*)d_in[6];
  const float* bg2 = (const float*)d_in[7];
  const float* W2  = (const float*)d_in[8];
  const float* b2  = (const float*)d_in[9];
  const float* W3  = (const float*)d_in[10];
  const float* b3  = (const float*)d_in[11];
  float* out = (float*)d_out;

  const int K1 = in_sizes[2] / HDIM;  // 128
  const int N  = in_sizes[0] / K1;    // 50000
  const int E  = in_sizes[1] / 2;     // 300000

  char* w = (char*)d_ws;
  auto alloc = [&](size_t bytes) -> char* {
    char* p = w;
    w += (bytes + 255) & ~(size_t)255;
    return p;
  };
  unsigned short* PH = (unsigned short*)alloc((size_t)N * HDIM * 2);
  unsigned short* PL = (unsigned short*)alloc((size_t)N * HDIM * 2);
  float* dinv   = (float*)alloc((size_t)N * sizeof(float));
  int*   deg    = (int*)alloc((size_t)N * sizeof(int));
  int*   rowptr = (int*)alloc((size_t)(N + 1) * sizeof(int));
  int*   cursor = (int*)alloc((size_t)N * sizeof(int));
  int*   col    = (int*)alloc((size_t)E * sizeof(int));
  const int nb  = (N + 255) / 256;
  int*   bsum   = (int*)alloc((size_t)nb * sizeof(int));
  int*   boff   = (int*)alloc((size_t)nb * sizeof(int));
  unsigned short* W1sH  = (unsigned short*)alloc((size_t)HDIM * K1 * 2);
  unsigned short* W1sL  = (unsigned short*)alloc((size_t)HDIM * K1 * 2);
  unsigned short* Wg1sH = (unsigned short*)alloc((size_t)HDIM * HDIM * 2);
  unsigned short* Wg1sL = (unsigned short*)alloc((size_t)HDIM * HDIM * 2);
  unsigned short* Wg2sH = (unsigned short*)alloc((size_t)HDIM * HDIM * 2);
  unsigned short* Wg2sL = (unsigned short*)alloc((size_t)HDIM * HDIM * 2);
  unsigned short* W2sH  = (unsigned short*)alloc((size_t)HDIM * HDIM * 2);
  unsigned short* W2sL  = (unsigned short*)alloc((size_t)HDIM * HDIM * 2);
  unsigned short* W3sH  = (unsigned short*)alloc((size_t)HDIM * HDIM * 2);
  unsigned short* W3sL  = (unsigned short*)alloc((size_t)HDIM * HDIM * 2);

  unsigned short* QH = (unsigned short*)out;
  unsigned short* QL = QH + (size_t)N * HDIM;

  const int ge = (E + 255) / 256;
  const int gn = (N + 255) / 256;

  prep_w_staged<<<(K1 * 32 + 255) / 256, 256, 0, stream>>>(W1, W1sH, W1sL, K1);
  prep_w_staged<<<(HDIM * 32 + 255) / 256, 256, 0, stream>>>(Wg1, Wg1sH, Wg1sL, HDIM);
  prep_w_staged<<<(HDIM * 32 + 255) / 256, 256, 0, stream>>>(Wg2, Wg2sH, Wg2sL, HDIM);
  prep_w_staged<<<(HDIM * 32 + 255) / 256, 256, 0, stream>>>(W2, W2sH, W2sL, HDIM);
  prep_w_staged<<<(HDIM * 32 + 255) / 256, 256, 0, stream>>>(W3, W3sH, W3sL, HDIM);

  hipMemsetAsync(deg, 0, (size_t)N * sizeof(int), stream);
  deg_count_kernel<<<ge, 256, 0, stream>>>(ei, deg, E);
  dinv_kernel<<<gn, 256, 0, stream>>>(deg, dinv, N);
  block_sum_kernel<<<nb, 256, 0, stream>>>(deg, bsum, N);
  scan_bsums_kernel<<<1, 256, 0, stream>>>(bsum, boff, rowptr, nb, N);
  scan_final_kernel<<<nb, 256, 0, stream>>>(deg, boff, rowptr, cursor, N);
  fill_csr_kernel<<<ge, 256, 0, stream>>>(ei, cursor, col, E);

  dim3 ggrid(2, (N + 127) / 128);
  const int gagg = (N + 3) / 4;
  const int gfuse = (N + 127) / 128;

  // h0 = relu(x@W1+b1) -> planes P
  mfma_gemm_splitA<true, true><<<ggrid, 256, 0, stream>>>(x, W1sH, W1sL, b1, PH, PL, N, K1);
  // t1 = h0@Wg1 -> out (fp32 scratch in d_out)  [pipelined]
  mfma_gemm_pp<false, false, false><<<ggrid, 256, 0, stream>>>(PH, PL, Wg1sH, Wg1sL, nullptr, out, nullptr, nullptr, N);
  // h1 = relu(agg(t1)+bg1) -> planes P
  aggregate_b<<<gagg, 256, 0, stream>>>(out, dinv, rowptr, col, bg1, PH, PL, N);
  // t2 = h1@Wg2 -> out  [pipelined]
  mfma_gemm_pp<false, false, false><<<ggrid, 256, 0, stream>>>(PH, PL, Wg2sH, Wg2sL, nullptr, out, nullptr, nullptr, N);
  // h2 = relu(agg(t2)+bg2) -> planes P
  aggregate_b<<<gagg, 256, 0, stream>>>(out, dinv, rowptr, col, bg2, PH, PL, N);
  // h3 = relu(h2@W2+b2) -> planes Q (d_out bytes)  [pipelined]
  mfma_gemm_pp<true, true, true><<<ggrid, 256, 0, stream>>>(PH, PL, W2sH, W2sL, b2, nullptr, QH, QL, N);
  // out = softmax(h3@W3+b3), fused, in-place on d_out
  mfma_gemm_softmax<<<gfuse, 512, 0, stream>>>(QH, QL, W3sH, W3sL, b3, out, N, HDIM);
}